// Round 1
// baseline (52.966 us; speedup 1.0000x reference)
//
#include <hip/hip_runtime.h>

#define NJ 32
#define GRAVZ 9.81f

struct V3 { float x, y, z; };

__device__ __forceinline__ V3 mkv3(float x, float y, float z){ V3 r; r.x=x; r.y=y; r.z=z; return r; }
__device__ __forceinline__ V3 vadd(V3 a, V3 b){ return mkv3(a.x+b.x, a.y+b.y, a.z+b.z); }
__device__ __forceinline__ V3 vsub(V3 a, V3 b){ return mkv3(a.x-b.x, a.y-b.y, a.z-b.z); }
__device__ __forceinline__ V3 vscl(float s, V3 a){ return mkv3(s*a.x, s*a.y, s*a.z); }
__device__ __forceinline__ V3 vcross(V3 a, V3 b){
    return mkv3(a.y*b.z - a.z*b.y, a.z*b.x - a.x*b.z, a.x*b.y - a.y*b.x);
}
// Rt*v with R=rot_z(q): Rt = [[c,s,0],[-s,c,0],[0,0,1]]
__device__ __forceinline__ V3 rtv(float c, float s, V3 v){ return mkv3(c*v.x + s*v.y, c*v.y - s*v.x, v.z); }
// R*v
__device__ __forceinline__ V3 rv (float c, float s, V3 v){ return mkv3(c*v.x - s*v.y, s*v.x + c*v.y, v.z); }

__global__ __launch_bounds__(256) void rnea_kernel(
    const float* __restrict__ q,
    const float* __restrict__ qd,
    const float* __restrict__ qdd,
    const float* __restrict__ trans,
    const float* __restrict__ mass,
    const float* __restrict__ com,
    const float* __restrict__ inertia,
    const float* __restrict__ damping,
    float* __restrict__ out,
    int Bn)
{
    int b = blockIdx.x * blockDim.x + threadIdx.x;
    if (b >= Bn) return;
    size_t base = (size_t)b * NJ;

    // Vectorized row loads (rows are 128B-aligned, one cache line each).
    float qv[NJ], qdv[NJ], qddv[NJ];
    #pragma unroll
    for (int i = 0; i < NJ/4; ++i) {
        float4 a0 = reinterpret_cast<const float4*>(q   + base)[i];
        float4 a1 = reinterpret_cast<const float4*>(qd  + base)[i];
        float4 a2 = reinterpret_cast<const float4*>(qdd + base)[i];
        qv  [4*i+0]=a0.x; qv  [4*i+1]=a0.y; qv  [4*i+2]=a0.z; qv  [4*i+3]=a0.w;
        qdv [4*i+0]=a1.x; qdv [4*i+1]=a1.y; qdv [4*i+2]=a1.z; qdv [4*i+3]=a1.w;
        qddv[4*i+0]=a2.x; qddv[4*i+1]=a2.y; qddv[4*i+2]=a2.z; qddv[4*i+3]=a2.w;
    }

    float cv[NJ], sv[NJ];
    V3 vl = mkv3(0,0,0), va = mkv3(0,0,0), al = mkv3(0,0,GRAVZ), aa = mkv3(0,0,0);

    // ---- Forward scan: keep only live state; stash (c,s) per joint. ----
    #pragma unroll
    for (int j = 0; j < NJ; ++j) {
        float s, c;
        __sincosf(qv[j], &s, &c);
        cv[j]=c; sv[j]=s;
        V3 p  = mkv3(trans[3*j+0], trans[3*j+1], trans[3*j+2]);   // uniform -> SGPR
        V3 t  = vscl(-1.f, rtv(c, s, p));
        V3 wv = rtv(c, s, va);
        V3 lv = vadd(vcross(t, wv), rtv(c, s, vl));
        V3 wa = rtv(c, s, aa);
        V3 la = vadd(vcross(t, wa), rtv(c, s, al));
        float qdj = qdv[j], qddj = qddv[j];
        va = mkv3(wv.x, wv.y, wv.z + qdj);
        vl = lv;
        // cross(va_n, (0,0,qd)) = (va.y*qd, -va.x*qd, 0)
        aa = mkv3(wa.x + va.y*qdj, wa.y - va.x*qdj, wa.z + qddj);
        al = mkv3(la.x + vl.y*qdj, la.y - vl.x*qdj, la.z);
    }

    // ---- Backward scan with exact state inversion (no stored trajectory). ----
    V3 gl = mkv3(0,0,0), ga = mkv3(0,0,0);
    float tau[NJ];

    #pragma unroll
    for (int j = NJ-1; j >= 0; --j) {
        float m = mass[j];
        V3 cm = mkv3(com[3*j+0], com[3*j+1], com[3*j+2]);
        V3 mc = vscl(m, cm);
        float cc = cm.x*cm.x + cm.y*cm.y + cm.z*cm.z;
        const float* I = inertia + 9*j;
        // Ibar = inertia + m*(|c|^2 I - c c^T)   (skew(c) skew(c)^T identity)
        float I00 = I[0] + m*(cc - cm.x*cm.x);
        float I01 = I[1] - m*(cm.x*cm.y);
        float I02 = I[2] - m*(cm.x*cm.z);
        float I10 = I[3] - m*(cm.y*cm.x);
        float I11 = I[4] + m*(cc - cm.y*cm.y);
        float I12 = I[5] - m*(cm.y*cm.z);
        float I20 = I[6] - m*(cm.z*cm.x);
        float I21 = I[7] - m*(cm.z*cm.y);
        float I22 = I[8] + m*(cc - cm.z*cm.z);

        V3 fa_l = vadd(vscl(m, al), vcross(mc, aa));
        V3 Iaa = mkv3(I00*aa.x + I01*aa.y + I02*aa.z,
                      I10*aa.x + I11*aa.y + I12*aa.z,
                      I20*aa.x + I21*aa.y + I22*aa.z);
        V3 fa_a = vadd(Iaa, vcross(mc, al));
        V3 fv_l = vadd(vscl(m, vl), vcross(mc, va));
        V3 Iva = mkv3(I00*va.x + I01*va.y + I02*va.z,
                      I10*va.x + I11*va.y + I12*va.z,
                      I20*va.x + I21*va.y + I22*va.z);
        V3 fv_a = vadd(Iva, vcross(mc, vl));
        V3 cf_a = vadd(vcross(va, fv_a), vcross(vl, fv_l));
        V3 cf_l = vcross(va, fv_l);
        V3 f_l = vadd(vadd(fa_l, cf_l), gl);
        V3 f_a = vadd(vadd(fa_a, cf_a), ga);
        tau[j] = f_a.z;

        float c = cv[j], s = sv[j];
        V3 p = mkv3(trans[3*j+0], trans[3*j+1], trans[3*j+2]);
        V3 Rf = rv(c, s, f_l);
        gl = Rf;
        ga = vadd(vcross(p, Rf), rv(c, s, f_a));

        if (j > 0) {
            // Invert the forward step: recover state after joint j-1.
            float qdj = qdv[j], qddj = qddv[j];
            V3 wv = mkv3(va.x, va.y, va.z - qdj);
            V3 wa = mkv3(aa.x - va.y*qdj, aa.y + va.x*qdj, aa.z - qddj);
            V3 la = mkv3(al.x - vl.y*qdj, al.y + vl.x*qdj, al.z);
            V3 t  = vscl(-1.f, rtv(c, s, p));
            V3 vlp = rv(c, s, vsub(vl, vcross(t, wv)));
            V3 alp = rv(c, s, vsub(la, vcross(t, wa)));
            va = rv(c, s, wv);
            aa = rv(c, s, wa);
            vl = vlp;
            al = alp;
        }
    }

    #pragma unroll
    for (int i = 0; i < NJ/4; ++i) {
        float4 o;
        o.x = tau[4*i+0] + damping[4*i+0]*qdv[4*i+0];
        o.y = tau[4*i+1] + damping[4*i+1]*qdv[4*i+1];
        o.z = tau[4*i+2] + damping[4*i+2]*qdv[4*i+2];
        o.w = tau[4*i+3] + damping[4*i+3]*qdv[4*i+3];
        reinterpret_cast<float4*>(out + base)[i] = o;
    }
}

extern "C" void kernel_launch(void* const* d_in, const int* in_sizes, int n_in,
                              void* d_out, int out_size, void* d_ws, size_t ws_size,
                              hipStream_t stream) {
    const float* q       = (const float*)d_in[0];
    const float* qd      = (const float*)d_in[1];
    const float* qdd     = (const float*)d_in[2];
    const float* trans   = (const float*)d_in[3];
    const float* mass    = (const float*)d_in[4];
    const float* com     = (const float*)d_in[5];
    const float* inertia = (const float*)d_in[6];
    const float* damping = (const float*)d_in[7];
    float* out = (float*)d_out;

    int Bn = in_sizes[0] / NJ;
    int block = 256;
    int grid = (Bn + block - 1) / block;
    hipLaunchKernelGGL(rnea_kernel, dim3(grid), dim3(block), 0, stream,
                       q, qd, qdd, trans, mass, com, inertia, damping, out, Bn);
}

// Round 2
// 36.617 us; speedup vs baseline: 1.4465x; 1.4465x over previous
//
#include <hip/hip_runtime.h>

#define NJ 32
#define GRAVZ 9.81f

struct V3 { float x, y, z; };

__device__ __forceinline__ V3 mkv3(float x, float y, float z){ V3 r; r.x=x; r.y=y; r.z=z; return r; }
__device__ __forceinline__ V3 vadd(V3 a, V3 b){ return mkv3(a.x+b.x, a.y+b.y, a.z+b.z); }
__device__ __forceinline__ V3 vsub(V3 a, V3 b){ return mkv3(a.x-b.x, a.y-b.y, a.z-b.z); }
__device__ __forceinline__ V3 vscl(float s, V3 a){ return mkv3(s*a.x, s*a.y, s*a.z); }
__device__ __forceinline__ V3 vcross(V3 a, V3 b){
    return mkv3(a.y*b.z - a.z*b.y, a.z*b.x - a.x*b.z, a.x*b.y - a.y*b.x);
}
// Rt*v with R=rot_z(q): Rt = [[c,s,0],[-s,c,0],[0,0,1]]
__device__ __forceinline__ V3 rtv(float c, float s, V3 v){ return mkv3(c*v.x + s*v.y, c*v.y - s*v.x, v.z); }
// R*v
__device__ __forceinline__ V3 rv (float c, float s, V3 v){ return mkv3(c*v.x - s*v.y, s*v.x + c*v.y, v.z); }

// Per-joint uniform precompute: Ibar (9) + m*com (3) -> ws[12*j ..]
__global__ void precomp_kernel(const float* __restrict__ mass,
                               const float* __restrict__ com,
                               const float* __restrict__ inertia,
                               float* __restrict__ ws)
{
    int j = threadIdx.x;
    if (j >= NJ) return;
    float m  = mass[j];
    float cx = com[3*j+0], cy = com[3*j+1], cz = com[3*j+2];
    float cc = cx*cx + cy*cy + cz*cz;
    const float* I = inertia + 9*j;
    float* o = ws + 12*j;
    o[0] = I[0] + m*(cc - cx*cx);
    o[1] = I[1] - m*(cx*cy);
    o[2] = I[2] - m*(cx*cz);
    o[3] = I[3] - m*(cy*cx);
    o[4] = I[4] + m*(cc - cy*cy);
    o[5] = I[5] - m*(cy*cz);
    o[6] = I[6] - m*(cz*cx);
    o[7] = I[7] - m*(cz*cy);
    o[8] = I[8] + m*(cc - cz*cz);
    o[9]  = m*cx;
    o[10] = m*cy;
    o[11] = m*cz;
}

__global__ __launch_bounds__(256) void rnea_kernel(
    const float* __restrict__ q,
    const float* __restrict__ qd,
    const float* __restrict__ qdd,
    const float* __restrict__ trans,
    const float* __restrict__ mass,
    const float* __restrict__ damping,
    const float* __restrict__ pre,   // 12 floats per joint: Ibar row-major, then m*com
    float* __restrict__ out,
    int Bn)
{
    int b = blockIdx.x * blockDim.x + threadIdx.x;
    if (b >= Bn) return;
    size_t base = (size_t)b * NJ;

    // Preload q/qd/qdd rows (one 128B line each) as float4; arrays are
    // statically indexed under full unroll -> registers, and die as the
    // forward scan consumes them (cv/sv grow in their place).
    float qv[NJ], qdv[NJ], qddv[NJ];
    #pragma unroll
    for (int i = 0; i < NJ/4; ++i) {
        float4 a0 = reinterpret_cast<const float4*>(q   + base)[i];
        float4 a1 = reinterpret_cast<const float4*>(qd  + base)[i];
        float4 a2 = reinterpret_cast<const float4*>(qdd + base)[i];
        qv  [4*i+0]=a0.x; qv  [4*i+1]=a0.y; qv  [4*i+2]=a0.z; qv  [4*i+3]=a0.w;
        qdv [4*i+0]=a1.x; qdv [4*i+1]=a1.y; qdv [4*i+2]=a1.z; qdv [4*i+3]=a1.w;
        qddv[4*i+0]=a2.x; qddv[4*i+1]=a2.y; qddv[4*i+2]=a2.z; qddv[4*i+3]=a2.w;
    }

    float cv[NJ], sv[NJ];
    V3 vl = mkv3(0,0,0), va = mkv3(0,0,0), al = mkv3(0,0,GRAVZ), aa = mkv3(0,0,0);

    // ---- Forward scan: keep only live 12-float state; stash (c,s). ----
    #pragma unroll
    for (int j = 0; j < NJ; ++j) {
        float s, c;
        __sincosf(qv[j], &s, &c);
        cv[j]=c; sv[j]=s;
        V3 p  = mkv3(trans[3*j+0], trans[3*j+1], trans[3*j+2]);   // uniform -> SGPR
        V3 t  = vscl(-1.f, rtv(c, s, p));
        V3 wv = rtv(c, s, va);
        V3 lv = vadd(vcross(t, wv), rtv(c, s, vl));
        V3 wa = rtv(c, s, aa);
        V3 la = vadd(vcross(t, wa), rtv(c, s, al));
        float qdj = qdv[j], qddj = qddv[j];
        va = mkv3(wv.x, wv.y, wv.z + qdj);
        vl = lv;
        // cross(va_n, (0,0,qd)) = (va.y*qd, -va.x*qd, 0)
        aa = mkv3(wa.x + va.y*qdj, wa.y - va.x*qdj, wa.z + qddj);
        al = mkv3(la.x + vl.y*qdj, la.y - vl.x*qdj, la.z);
    }

    // ---- Backward scan with exact state inversion (no stored trajectory,
    //      no tau array; qd/qdd reloaded off the critical path). ----
    V3 gl = mkv3(0,0,0), ga = mkv3(0,0,0);

    #pragma unroll
    for (int j = NJ-1; j >= 0; --j) {
        float m = mass[j];                        // uniform -> SGPR
        const float* w = pre + 12*j;              // uniform -> s_load
        float I00=w[0], I01=w[1], I02=w[2];
        float I10=w[3], I11=w[4], I12=w[5];
        float I20=w[6], I21=w[7], I22=w[8];
        V3 mc = mkv3(w[9], w[10], w[11]);

        float qdj  = qd [base + j];               // L1/L2 hit, off dep chain
        float qddj = qdd[base + j];

        V3 fa_l = vadd(vscl(m, al), vcross(mc, aa));
        V3 Iaa = mkv3(I00*aa.x + I01*aa.y + I02*aa.z,
                      I10*aa.x + I11*aa.y + I12*aa.z,
                      I20*aa.x + I21*aa.y + I22*aa.z);
        V3 fa_a = vadd(Iaa, vcross(mc, al));
        V3 fv_l = vadd(vscl(m, vl), vcross(mc, va));
        V3 Iva = mkv3(I00*va.x + I01*va.y + I02*va.z,
                      I10*va.x + I11*va.y + I12*va.z,
                      I20*va.x + I21*va.y + I22*va.z);
        V3 fv_a = vadd(Iva, vcross(mc, vl));
        V3 cf_a = vadd(vcross(va, fv_a), vcross(vl, fv_l));
        V3 cf_l = vcross(va, fv_l);
        V3 f_l = vadd(vadd(fa_l, cf_l), gl);
        V3 f_a = vadd(vadd(fa_a, cf_a), ga);

        out[base + j] = f_a.z + damping[j] * qdj;   // direct store, no tau array

        float c = cv[j], s = sv[j];
        V3 p = mkv3(trans[3*j+0], trans[3*j+1], trans[3*j+2]);
        V3 Rf = rv(c, s, f_l);
        gl = Rf;
        ga = vadd(vcross(p, Rf), rv(c, s, f_a));

        if (j > 0) {
            // Invert the forward step: recover state after joint j-1.
            V3 wv = mkv3(va.x, va.y, va.z - qdj);
            V3 wa = mkv3(aa.x - va.y*qdj, aa.y + va.x*qdj, aa.z - qddj);
            V3 la = mkv3(al.x - vl.y*qdj, al.y + vl.x*qdj, al.z);
            V3 t  = vscl(-1.f, rtv(c, s, p));
            V3 vlp = rv(c, s, vsub(vl, vcross(t, wv)));
            V3 alp = rv(c, s, vsub(la, vcross(t, wa)));
            va = rv(c, s, wv);
            aa = rv(c, s, wa);
            vl = vlp;
            al = alp;
        }
    }
}

extern "C" void kernel_launch(void* const* d_in, const int* in_sizes, int n_in,
                              void* d_out, int out_size, void* d_ws, size_t ws_size,
                              hipStream_t stream) {
    const float* q       = (const float*)d_in[0];
    const float* qd      = (const float*)d_in[1];
    const float* qdd     = (const float*)d_in[2];
    const float* trans   = (const float*)d_in[3];
    const float* mass    = (const float*)d_in[4];
    const float* com     = (const float*)d_in[5];
    const float* inertia = (const float*)d_in[6];
    const float* damping = (const float*)d_in[7];
    float* out = (float*)d_out;
    float* pre = (float*)d_ws;   // 32*12 floats = 1536 B

    hipLaunchKernelGGL(precomp_kernel, dim3(1), dim3(64), 0, stream,
                       mass, com, inertia, pre);

    int Bn = in_sizes[0] / NJ;
    int block = 256;
    int grid = (Bn + block - 1) / block;
    hipLaunchKernelGGL(rnea_kernel, dim3(grid), dim3(block), 0, stream,
                       q, qd, qdd, trans, mass, damping, pre, out, Bn);
}